// Round 10
// baseline (440.341 us; speedup 1.0000x reference)
//
#include <hip/hip_runtime.h>
#include <hip/hip_bf16.h>

typedef __hip_bfloat16 bf16;
typedef __attribute__((ext_vector_type(8))) short short8;
typedef __attribute__((ext_vector_type(4))) float f32x4;

#define DEV __device__ __forceinline__

DEV float blo(unsigned u) { return __uint_as_float(u << 16); }
DEV float bhi(unsigned u) { return __uint_as_float(u & 0xffff0000u); }

DEV float waveReduceSum(float v) {
#pragma unroll
    for (int m = 1; m < 64; m <<= 1) v += __shfl_xor(v, m);
    return v;
}

DEV float red8(float v) {  // sum over the 8 lanes with stride 8 (same head)
    v += __shfl_xor(v, 8);
    v += __shfl_xor(v, 16);
    v += __shfl_xor(v, 32);
    return v;
}

// ---------------- fused one-time prep: weight packing + bias packing + Me ----------------
// section A: pack W{q,k,v,skip} into MFMA B-fragment order  (4*L*16384 threads)
// section B: pack biases                                     (4*L*128 threads)
// section C: Me[l][j][n] rank-3 edge matrices                (L*4*128 threads)
__global__ __launch_bounds__(256) void prep_k(
    const float* __restrict__ Wq, const float* __restrict__ Wk,
    const float* __restrict__ Wv, const float* __restrict__ Ws,
    const float* __restrict__ bq, const float* __restrict__ bk,
    const float* __restrict__ bv, const float* __restrict__ bs,
    const float* __restrict__ edge_w, const float* __restrict__ edge_b,
    const float* __restrict__ We,
    bf16* __restrict__ Wpack, float* __restrict__ bpack, float* __restrict__ Me, int L) {
    int t = blockIdx.x * 256 + threadIdx.x;
    int tA = 4 * L * 16384, tB = 4 * L * 128, tC = L * 4 * 128;
    if (t < tA) {
        int p = t & 16383;
        int ls = t >> 14;
        int l = ls >> 2, s = ls & 3;
        int j = p & 7, ln = (p >> 3) & 63, kb = (p >> 9) & 3, nb = p >> 11;
        int k = kb * 32 + (ln >> 4) * 8 + j;
        int n = nb * 16 + (ln & 15);
        const float* W = (s == 0) ? Wq : (s == 1) ? Wk : (s == 2) ? Wv : Ws;
        Wpack[t] = __float2bfloat16(W[(size_t)l * 16384 + k * 128 + n]);
        return;
    }
    t -= tA;
    if (t < tB) {
        int d = t & 127;
        int ls = t >> 7;
        int l = ls >> 2, s = ls & 3;
        const float* B = (s == 0) ? bq : (s == 1) ? bk : (s == 2) ? bv : bs;
        bpack[t] = B[l * 128 + d];
        return;
    }
    t -= tB;
    if (t < tC) {
        int n = t & 127, j = (t >> 7) & 3, l = t >> 9;
        const float* W = We + (size_t)l * 16384;
        const float* row = (j < 3) ? (edge_w + j * 128) : edge_b;
        float acc = 0.f;
        for (int d = 0; d < 128; ++d) acc += row[d] * W[d * 128 + n];
        Me[t] = acc;
    }
}

// ---------------- CSR build ----------------
__global__ __launch_bounds__(256) void hist_k(const int* __restrict__ ei,
                                              int* __restrict__ deg, int E) {
    int e = blockIdx.x * 256 + threadIdx.x;
    if (e >= E) return;
    atomicAdd(&deg[ei[E + e]], 1);
}

__global__ __launch_bounds__(1024) void scan_k(const int* __restrict__ deg,
                                               int* __restrict__ off,
                                               int* __restrict__ cursor, int N, int E) {
    __shared__ int part[1024];
    int t = threadIdx.x;
    int chunk = (N + 1023) >> 10;
    int lo = t * chunk, hi = min(lo + chunk, N);
    int s = 0;
    for (int i = lo; i < hi; ++i) s += deg[i];
    part[t] = s;
    __syncthreads();
    for (int d = 1; d < 1024; d <<= 1) {
        int v = (t >= d) ? part[t - d] : 0;
        __syncthreads();
        part[t] += v;
        __syncthreads();
    }
    int base = (t == 0) ? 0 : part[t - 1];
    for (int i = lo; i < hi; ++i) {
        off[i] = base;
        cursor[i] = base;
        base += deg[i];
    }
    if (t == 1023) off[N] = E;
}

// scatter fused edge record {src-as-int-bits, a0, a1, a2} into CSR position order
__global__ __launch_bounds__(256) void fill_k(const int* __restrict__ ei,
                                              const float* __restrict__ eattr,
                                              int* __restrict__ cursor,
                                              float4* __restrict__ ea4, int E) {
    int e = blockIdx.x * 256 + threadIdx.x;
    if (e >= E) return;
    int dst = ei[E + e];
    int pos = atomicAdd(&cursor[dst], 1);
    ea4[pos] = make_float4(__int_as_float(ei[e]),
                           eattr[e * 3], eattr[e * 3 + 1], eattr[e * 3 + 2]);
}

// ---------------- node encoder ----------------
__global__ __launch_bounds__(256) void node_enc_k(
    const float* __restrict__ x, const float* __restrict__ w,
    const float* __restrict__ b, float* __restrict__ h,
    bf16* __restrict__ h_bf, int N) {
    int t = blockIdx.x * 256 + threadIdx.x;
    if (t >= N * 128) return;
    int n = t >> 7, d = t & 127;
    float acc = b[d];
#pragma unroll
    for (int i = 0; i < 9; ++i) acc += x[n * 9 + i] * w[i * 128 + d];
    float r = fmaxf(acc, 0.f);
    h[t] = r;
    h_bf[t] = __float2bfloat16(r);
}

// ---------------- fused QKVS MFMA GEMM: [M,128] x [128,128] x4 ----------------
// Q -> [n][128] bf16; K,V -> kv [n][8 heads][16 K | 16 V] bf16 (64 B per head);
// S -> f32 [n][128]
__global__ __launch_bounds__(256) void qkvs_k(
    const bf16* __restrict__ A, const bf16* __restrict__ Wp,
    const float* __restrict__ bp,
    bf16* __restrict__ Q, bf16* __restrict__ kv,
    float* __restrict__ S, int M) {
    int tid = threadIdx.x;
    int l = tid & 63, w = tid >> 6;
    int row0 = blockIdx.x * 64;
    const short* Ab = (const short*)A + (size_t)(row0 + (l & 15)) * 128 + ((l >> 4) * 8);
    short8 a[4][4];
#pragma unroll
    for (int mb = 0; mb < 4; ++mb)
#pragma unroll
        for (int kb = 0; kb < 4; ++kb)
            a[mb][kb] = *(const short8*)(Ab + mb * 16 * 128 + kb * 32);
    int colb = w * 32 + (l & 15);
#pragma unroll
    for (int s = 0; s < 4; ++s) {
        const short* Wb = (const short*)Wp + s * 16384;
        short8 bfr[2][4];
#pragma unroll
        for (int nbi = 0; nbi < 2; ++nbi)
#pragma unroll
            for (int kb = 0; kb < 4; ++kb)
                bfr[nbi][kb] = *(const short8*)(Wb + (size_t)(((w * 2 + nbi) * 4 + kb) * 64 + l) * 8);
        f32x4 acc[4][2] = {};
#pragma unroll
        for (int kb = 0; kb < 4; ++kb)
#pragma unroll
            for (int mb = 0; mb < 4; ++mb)
#pragma unroll
                for (int nbi = 0; nbi < 2; ++nbi)
                    acc[mb][nbi] = __builtin_amdgcn_mfma_f32_16x16x32_bf16(
                        a[mb][kb], bfr[nbi][kb], acc[mb][nbi], 0, 0, 0);
        float bias0 = bp[s * 128 + colb];
        float bias1 = bp[s * 128 + colb + 16];
#pragma unroll
        for (int mb = 0; mb < 4; ++mb) {
            int rbase = row0 + mb * 16 + (l >> 4) * 4;
#pragma unroll
            for (int j = 0; j < 4; ++j) {
                int r = rbase + j;
                if (r >= M) continue;
#pragma unroll
                for (int nbi = 0; nbi < 2; ++nbi) {
                    int c = colb + nbi * 16;
                    float v = acc[mb][nbi][j] + (nbi ? bias1 : bias0);
                    if (s == 0) {
                        Q[(size_t)r * 128 + c] = __float2bfloat16(v);
                    } else if (s == 3) {
                        S[(size_t)r * 128 + c] = v;
                    } else {
                        // per-head interleave: head = c>>4, within = c&15
                        size_t idx = (size_t)r * 256 + (size_t)(c >> 4) * 32 + (c & 15)
                                   + ((s == 2) ? 16 : 0);
                        kv[idx] = __float2bfloat16(v);
                    }
                }
            }
        }
    }
}

// ---------------- fused attention + beta gate + residual + layernorm ----------------
// one wave per node; 64 lanes = 8 edge-slots x 8 heads; lane owns a head's 16 dims.
// qm inlined (R6-style); one fused 16B record {src, a0,a1,a2} per edge;
// KV row per-head interleaved: each lane reads ONE contiguous 64 B block.
__global__ __launch_bounds__(256) void attn_k(
    const int* __restrict__ off, const float4* __restrict__ ea4,
    const float* __restrict__ Me, const bf16* __restrict__ Q,
    const bf16* __restrict__ kv, const float* __restrict__ S,
    float* __restrict__ h, bf16* __restrict__ h_bf,
    const float* __restrict__ Wb, const float* __restrict__ lng,
    const float* __restrict__ lnb, int N) {
    int gw = (blockIdx.x * 256 + threadIdx.x) >> 6;
    int l = threadIdx.x & 63;
    int nw = (gridDim.x * 256) >> 6;
    int hh = l & 7, sl = l >> 3;
    int d0 = hh * 16 + sl * 2, d1 = d0 + 1;
    float me00 = Me[d0],       me01 = Me[d1];
    float me10 = Me[128 + d0], me11 = Me[128 + d1];
    float me20 = Me[256 + d0], me21 = Me[256 + d1];
    float me30 = Me[384 + d0], me31 = Me[384 + d1];
    float wba0 = Wb[d0],       wba1 = Wb[d1];
    float wbb0 = Wb[128 + d0], wbb1 = Wb[128 + d1];
    float wbc0 = Wb[256 + d0], wbc1 = Wb[256 + d1];
    float g0 = lng[d0], g1 = lng[d1];
    float bb0 = lnb[d0], bb1 = lnb[d1];
    for (int n = gw; n < N; n += nw) {
        const unsigned* qr = (const unsigned*)Q + (size_t)n * 64 + hh * 8;
        unsigned qq[8];
        *(uint4*)&qq[0] = *(const uint4*)qr;
        *(uint4*)&qq[4] = *(const uint4*)(qr + 4);
        float q[16];
#pragma unroll
        for (int k = 0; k < 8; ++k) { q[2 * k] = blo(qq[k]); q[2 * k + 1] = bhi(qq[k]); }
        // qm_j = q . Me_j over this head's 16 dims (redundant across sl lanes, free)
        float qm0 = 0.f, qm1 = 0.f, qm2 = 0.f, qm3 = 0.f;
#pragma unroll
        for (int c = 0; c < 4; ++c) {
            float4 r0 = *(const float4*)(Me + hh * 16 + c * 4);
            float4 r1 = *(const float4*)(Me + 128 + hh * 16 + c * 4);
            float4 r2 = *(const float4*)(Me + 256 + hh * 16 + c * 4);
            float4 r3 = *(const float4*)(Me + 384 + hh * 16 + c * 4);
            qm0 += q[c*4]*r0.x + q[c*4+1]*r0.y + q[c*4+2]*r0.z + q[c*4+3]*r0.w;
            qm1 += q[c*4]*r1.x + q[c*4+1]*r1.y + q[c*4+2]*r1.z + q[c*4+3]*r1.w;
            qm2 += q[c*4]*r2.x + q[c*4+1]*r2.y + q[c*4+2]*r2.z + q[c*4+3]*r2.w;
            qm3 += q[c*4]*r3.x + q[c*4+1]*r3.y + q[c*4+2]*r3.z + q[c*4+3]*r3.w;
        }
        float acc[16] = {};
        float S0 = 0.f, S1 = 0.f, S2 = 0.f, den = 0.f;
        int i0 = off[n], i1 = off[n + 1];
        int nit = (i1 - i0 + 7) >> 3;
        for (int it = 0; it < nit; ++it) {
            int idx = i0 + it * 8 + sl;
            bool ok = idx < i1;
            int ci = ok ? idx : i0;
            float4 rec = ea4[ci];                 // {src, a0, a1, a2} in one 16B load
            int src = __float_as_int(rec.x);
            const unsigned* kr = (const unsigned*)kv + (size_t)src * 128 + hh * 16;
            unsigned kk[8], vv[8];
            *(uint4*)&kk[0] = *(const uint4*)kr;
            *(uint4*)&kk[4] = *(const uint4*)(kr + 4);
            *(uint4*)&vv[0] = *(const uint4*)(kr + 8);
            *(uint4*)&vv[4] = *(const uint4*)(kr + 12);
            float sd = fmaf(rec.y, qm0, fmaf(rec.z, qm1, fmaf(rec.w, qm2, qm3)));
#pragma unroll
            for (int k = 0; k < 8; ++k)
                sd = fmaf(q[2 * k], blo(kk[k]), fmaf(q[2 * k + 1], bhi(kk[k]), sd));
            float p = ok ? __expf(sd * 0.25f) : 0.f;
            den += p;
            S0 = fmaf(p, rec.y, S0);
            S1 = fmaf(p, rec.z, S1);
            S2 = fmaf(p, rec.w, S2);
#pragma unroll
            for (int k = 0; k < 8; ++k) {
                acc[2 * k]     = fmaf(p, blo(vv[k]), acc[2 * k]);
                acc[2 * k + 1] = fmaf(p, bhi(vv[k]), acc[2 * k + 1]);
            }
        }
        // reduce over the 8 edge-slot lanes of each head
        den = red8(den); S0 = red8(S0); S1 = red8(S1); S2 = red8(S2);
#pragma unroll
        for (int k = 0; k < 16; ++k) acc[k] = red8(acc[k]);
        float inv = den > 0.f ? 1.f / den : 0.f;
        float o0 = (acc[sl * 2]     + S0 * me00 + S1 * me10 + S2 * me20 + den * me30) * inv;
        float o1 = (acc[sl * 2 + 1] + S0 * me01 + S1 * me11 + S2 * me21 + den * me31) * inv;
        size_t base = (size_t)n * 128;
        float s0 = S[base + d0], s1 = S[base + d1];
        float part = o0 * wba0 + s0 * wbb0 + (o0 - s0) * wbc0
                   + o1 * wba1 + s1 * wbb1 + (o1 - s1) * wbc1;
        float g = waveReduceSum(part);
        float beta = 1.f / (1.f + __expf(-g));
        float y0 = beta * s0 + (1.f - beta) * o0;
        float y1 = beta * s1 + (1.f - beta) * o1;
        float z0 = y0 + h[base + d0];
        float z1 = y1 + h[base + d1];
        float mean = waveReduceSum(z0 + z1) * (1.f / 128.f);
        float c0 = z0 - mean, c1 = z1 - mean;
        float var = waveReduceSum(c0 * c0 + c1 * c1) * (1.f / 128.f);
        float invs = rsqrtf(var + 1e-5f);
        float r0 = c0 * invs * g0 + bb0;
        float r1 = c1 * invs * g1 + bb1;
        h[base + d0] = r0;
        h[base + d1] = r1;
        h_bf[base + d0] = __float2bfloat16(r0);
        h_bf[base + d1] = __float2bfloat16(r1);
    }
}

// ---------------- two-stage pooling + head ----------------
__global__ __launch_bounds__(256) void pool_partial_k(
    const float* __restrict__ h, const int* __restrict__ batch,
    float* __restrict__ psum, int N) {
    int d = threadIdx.x & 127;
    int half = threadIdx.x >> 7;
    int n0 = blockIdx.x * 64;
    int n1 = min(n0 + 64, N);
    float acc = 0.f;
    int curg = -1;
    for (int n = n0 + half; n < n1; n += 2) {
        int g = batch[n];
        if (g != curg) {
            if (curg >= 0) atomicAdd(&psum[curg * 128 + d], acc);
            acc = 0.f;
            curg = g;
        }
        acc += h[(size_t)n * 128 + d];
    }
    if (curg >= 0) atomicAdd(&psum[curg * 128 + d], acc);
}

__global__ __launch_bounds__(128) void head2_k(
    const float* __restrict__ psum, const int* __restrict__ batch,
    const float* __restrict__ h1w, const float* __restrict__ h1b,
    const float* __restrict__ h2w, const float* __restrict__ h2b,
    float* __restrict__ out, int N) {
    int g = blockIdx.x;
    int t = threadIdx.x;
    auto lb = [&](int val) {
        int lo = 0, hi = N;
        while (lo < hi) {
            int mid = (lo + hi) >> 1;
            if (batch[mid] < val) lo = mid + 1; else hi = mid;
        }
        return lo;
    };
    int s = lb(g), e = lb(g + 1);
    float cnt = fmaxf((float)(e - s), 1.f);
    __shared__ float pl[128];
    __shared__ float hid[64];
    pl[t] = psum[g * 128 + t] / cnt;
    __syncthreads();
    if (t < 64) {
        float a = h1b[t];
        for (int k = 0; k < 128; ++k) a += pl[k] * h1w[k * 64 + t];
        hid[t] = fmaxf(a, 0.f);
    }
    __syncthreads();
    if (t < 10) {
        float o = h2b[t];
        for (int k = 0; k < 64; ++k) o += hid[k] * h2w[k * 10 + t];
        out[g * 10 + t] = o;
    }
}

extern "C" void kernel_launch(void* const* d_in, const int* in_sizes, int n_in,
                              void* d_out, int out_size, void* d_ws, size_t ws_size,
                              hipStream_t stream) {
    const float* x      = (const float*)d_in[0];
    const int*   ei     = (const int*)d_in[1];
    const float* eattr  = (const float*)d_in[2];
    const int*   batch  = (const int*)d_in[3];
    const float* node_w = (const float*)d_in[4];
    const float* node_b = (const float*)d_in[5];
    const float* edge_w = (const float*)d_in[6];
    const float* edge_b = (const float*)d_in[7];
    const float* Wq     = (const float*)d_in[8];
    const float* bq     = (const float*)d_in[9];
    const float* Wk     = (const float*)d_in[10];
    const float* bk     = (const float*)d_in[11];
    const float* Wv     = (const float*)d_in[12];
    const float* bv     = (const float*)d_in[13];
    const float* We     = (const float*)d_in[14];
    const float* Wskip  = (const float*)d_in[15];
    const float* bskip  = (const float*)d_in[16];
    const float* Wbeta  = (const float*)d_in[17];
    const float* ln_g   = (const float*)d_in[18];
    const float* ln_b   = (const float*)d_in[19];
    const float* h1_w   = (const float*)d_in[20];
    const float* h1_b   = (const float*)d_in[21];
    const float* h2_w   = (const float*)d_in[22];
    const float* h2_b   = (const float*)d_in[23];
    float* out = (float*)d_out;

    const int N = in_sizes[3];
    const int E = in_sizes[2] / 3;
    const int L = in_sizes[8] / 16384;
    const int G = out_size / 10;

    char* wptr = (char*)d_ws;
    auto alloc = [&](size_t bytes) {
        char* p = wptr;
        wptr += (bytes + 255) & ~(size_t)255;
        return p;
    };
    float* h      = (float*)alloc((size_t)(N + 64) * 128 * 4);
    bf16*  h_bf   = (bf16*)alloc((size_t)(N + 64) * 128 * 2);
    bf16*  Qb     = (bf16*)alloc((size_t)(N + 64) * 128 * 2);
    bf16*  kv     = (bf16*)alloc((size_t)(N + 64) * 256 * 2);
    float* S      = (float*)alloc((size_t)(N + 64) * 128 * 4);
    float4* ea4   = (float4*)alloc((size_t)E * 16);
    bf16*  Wpack  = (bf16*)alloc((size_t)4 * L * 16384 * 2);
    float* bpack  = (float*)alloc((size_t)4 * L * 128 * 4);
    float* Me     = (float*)alloc((size_t)L * 4 * 128 * 4);
    // deg + psum adjacent -> single memset covers both
    size_t degBytes = ((size_t)N * 4 + 255) & ~(size_t)255;
    char*  zblock = (char*)alloc(degBytes + (size_t)G * 128 * 4);
    int*   deg    = (int*)zblock;
    float* psum   = (float*)(zblock + degBytes);
    int*   off    = (int*)alloc((size_t)(N + 1) * 4);
    int*   cursor = (int*)alloc((size_t)N * 4);

    dim3 b256(256), b128(128);

    // one-time prep (single fused kernel + single memset)
    int prepTot = 4 * L * 16384 + 4 * L * 128 + L * 4 * 128;
    prep_k<<<(prepTot + 255) / 256, b256, 0, stream>>>(
        Wq, Wk, Wv, Wskip, bq, bk, bv, bskip, edge_w, edge_b, We,
        Wpack, bpack, Me, L);
    hipMemsetAsync(zblock, 0, degBytes + (size_t)G * 128 * 4, stream);
    hist_k<<<(E + 255) / 256, b256, 0, stream>>>(ei, deg, E);
    scan_k<<<1, 1024, 0, stream>>>(deg, off, cursor, N, E);
    fill_k<<<(E + 255) / 256, b256, 0, stream>>>(ei, eattr, cursor, ea4, E);
    node_enc_k<<<(N * 128 + 255) / 256, b256, 0, stream>>>(x, node_w, node_b, h, h_bf, N);

    int gN = (N + 63) / 64;
    int gAttn = (N + 3) / 4;
    for (int l = 0; l < L; ++l) {
        const float* Me_l = Me + (size_t)l * 512;
        qkvs_k<<<gN, b256, 0, stream>>>(h_bf, Wpack + (size_t)l * 4 * 16384,
                                        bpack + (size_t)l * 4 * 128, Qb, kv, S, N);
        attn_k<<<gAttn, b256, 0, stream>>>(off, ea4, Me_l, Qb, kv, S, h, h_bf,
                                           Wbeta + (size_t)l * 384,
                                           ln_g + (size_t)l * 128, ln_b + (size_t)l * 128, N);
    }

    pool_partial_k<<<gN, b256, 0, stream>>>(h, batch, psum, N);
    head2_k<<<G, b128, 0, stream>>>(psum, batch, h1_w, h1_b, h2_w, h2_b, out, N);
}

// Round 11
// 429.185 us; speedup vs baseline: 1.0260x; 1.0260x over previous
//
#include <hip/hip_runtime.h>
#include <hip/hip_bf16.h>

typedef __hip_bfloat16 bf16;
typedef __attribute__((ext_vector_type(8))) short short8;
typedef __attribute__((ext_vector_type(4))) float f32x4;

#define DEV __device__ __forceinline__

DEV float blo(unsigned u) { return __uint_as_float(u << 16); }
DEV float bhi(unsigned u) { return __uint_as_float(u & 0xffff0000u); }

DEV float waveReduceSum(float v) {
#pragma unroll
    for (int m = 1; m < 64; m <<= 1) v += __shfl_xor(v, m);
    return v;
}

DEV float red8(float v) {  // sum over the 8 lanes with stride 8 (same head)
    v += __shfl_xor(v, 8);
    v += __shfl_xor(v, 16);
    v += __shfl_xor(v, 32);
    return v;
}

// ---------------- fused one-time prep: weight packing + bias packing + Me ----------------
__global__ __launch_bounds__(256) void prep_k(
    const float* __restrict__ Wq, const float* __restrict__ Wk,
    const float* __restrict__ Wv, const float* __restrict__ Ws,
    const float* __restrict__ bq, const float* __restrict__ bk,
    const float* __restrict__ bv, const float* __restrict__ bs,
    const float* __restrict__ edge_w, const float* __restrict__ edge_b,
    const float* __restrict__ We,
    bf16* __restrict__ Wpack, float* __restrict__ bpack, float* __restrict__ Me, int L) {
    int t = blockIdx.x * 256 + threadIdx.x;
    int tA = 4 * L * 16384, tB = 4 * L * 128, tC = L * 4 * 128;
    if (t < tA) {
        int p = t & 16383;
        int ls = t >> 14;
        int l = ls >> 2, s = ls & 3;
        int j = p & 7, ln = (p >> 3) & 63, kb = (p >> 9) & 3, nb = p >> 11;
        int k = kb * 32 + (ln >> 4) * 8 + j;
        int n = nb * 16 + (ln & 15);
        const float* W = (s == 0) ? Wq : (s == 1) ? Wk : (s == 2) ? Wv : Ws;
        Wpack[t] = __float2bfloat16(W[(size_t)l * 16384 + k * 128 + n]);
        return;
    }
    t -= tA;
    if (t < tB) {
        int d = t & 127;
        int ls = t >> 7;
        int l = ls >> 2, s = ls & 3;
        const float* B = (s == 0) ? bq : (s == 1) ? bk : (s == 2) ? bv : bs;
        bpack[t] = B[l * 128 + d];
        return;
    }
    t -= tB;
    if (t < tC) {
        int n = t & 127, j = (t >> 7) & 3, l = t >> 9;
        const float* W = We + (size_t)l * 16384;
        const float* row = (j < 3) ? (edge_w + j * 128) : edge_b;
        float acc = 0.f;
        for (int d = 0; d < 128; ++d) acc += row[d] * W[d * 128 + n];
        Me[t] = acc;
    }
}

// ---------------- CSR build ----------------
__global__ __launch_bounds__(256) void hist_k(const int* __restrict__ ei,
                                              int* __restrict__ deg, int E) {
    int e = blockIdx.x * 256 + threadIdx.x;
    if (e >= E) return;
    atomicAdd(&deg[ei[E + e]], 1);
}

__global__ __launch_bounds__(1024) void scan_k(const int* __restrict__ deg,
                                               int* __restrict__ off,
                                               int* __restrict__ cursor, int N, int E) {
    __shared__ int part[1024];
    int t = threadIdx.x;
    int chunk = (N + 1023) >> 10;
    int lo = t * chunk, hi = min(lo + chunk, N);
    int s = 0;
    for (int i = lo; i < hi; ++i) s += deg[i];
    part[t] = s;
    __syncthreads();
    for (int d = 1; d < 1024; d <<= 1) {
        int v = (t >= d) ? part[t - d] : 0;
        __syncthreads();
        part[t] += v;
        __syncthreads();
    }
    int base = (t == 0) ? 0 : part[t - 1];
    for (int i = lo; i < hi; ++i) {
        off[i] = base;
        cursor[i] = base;
        base += deg[i];
    }
    if (t == 1023) off[N] = E;
}

// scatter src id + edge_attr (padded float4) into CSR position order
__global__ __launch_bounds__(256) void fill_k(const int* __restrict__ ei,
                                              const float* __restrict__ eattr,
                                              int* __restrict__ cursor,
                                              int* __restrict__ el_src,
                                              float4* __restrict__ ea4, int E) {
    int e = blockIdx.x * 256 + threadIdx.x;
    if (e >= E) return;
    int dst = ei[E + e];
    int pos = atomicAdd(&cursor[dst], 1);
    el_src[pos] = ei[e];
    ea4[pos] = make_float4(eattr[e * 3], eattr[e * 3 + 1], eattr[e * 3 + 2], 0.f);
}

// ---------------- node encoder ----------------
__global__ __launch_bounds__(256) void node_enc_k(
    const float* __restrict__ x, const float* __restrict__ w,
    const float* __restrict__ b, float* __restrict__ h,
    bf16* __restrict__ h_bf, int N) {
    int t = blockIdx.x * 256 + threadIdx.x;
    if (t >= N * 128) return;
    int n = t >> 7, d = t & 127;
    float acc = b[d];
#pragma unroll
    for (int i = 0; i < 9; ++i) acc += x[n * 9 + i] * w[i * 128 + d];
    float r = fmaxf(acc, 0.f);
    h[t] = r;
    h_bf[t] = __float2bfloat16(r);
}

// ---------------- fused QKVS MFMA GEMM: [M,128] x [128,128] x4 ----------------
// Q -> [n][128] bf16; K,V -> kv [n][256] bf16 (K row then V row); S -> f32
__global__ __launch_bounds__(256) void qkvs_k(
    const bf16* __restrict__ A, const bf16* __restrict__ Wp,
    const float* __restrict__ bp,
    bf16* __restrict__ Q, bf16* __restrict__ kv,
    float* __restrict__ S, int M) {
    int tid = threadIdx.x;
    int l = tid & 63, w = tid >> 6;
    int row0 = blockIdx.x * 64;
    const short* Ab = (const short*)A + (size_t)(row0 + (l & 15)) * 128 + ((l >> 4) * 8);
    short8 a[4][4];
#pragma unroll
    for (int mb = 0; mb < 4; ++mb)
#pragma unroll
        for (int kb = 0; kb < 4; ++kb)
            a[mb][kb] = *(const short8*)(Ab + mb * 16 * 128 + kb * 32);
    int colb = w * 32 + (l & 15);
#pragma unroll
    for (int s = 0; s < 4; ++s) {
        const short* Wb = (const short*)Wp + s * 16384;
        short8 bfr[2][4];
#pragma unroll
        for (int nbi = 0; nbi < 2; ++nbi)
#pragma unroll
            for (int kb = 0; kb < 4; ++kb)
                bfr[nbi][kb] = *(const short8*)(Wb + (size_t)(((w * 2 + nbi) * 4 + kb) * 64 + l) * 8);
        f32x4 acc[4][2] = {};
#pragma unroll
        for (int kb = 0; kb < 4; ++kb)
#pragma unroll
            for (int mb = 0; mb < 4; ++mb)
#pragma unroll
                for (int nbi = 0; nbi < 2; ++nbi)
                    acc[mb][nbi] = __builtin_amdgcn_mfma_f32_16x16x32_bf16(
                        a[mb][kb], bfr[nbi][kb], acc[mb][nbi], 0, 0, 0);
        float bias0 = bp[s * 128 + colb];
        float bias1 = bp[s * 128 + colb + 16];
#pragma unroll
        for (int mb = 0; mb < 4; ++mb) {
            int rbase = row0 + mb * 16 + (l >> 4) * 4;
#pragma unroll
            for (int j = 0; j < 4; ++j) {
                int r = rbase + j;
                if (r >= M) continue;
#pragma unroll
                for (int nbi = 0; nbi < 2; ++nbi) {
                    int c = colb + nbi * 16;
                    float v = acc[mb][nbi][j] + (nbi ? bias1 : bias0);
                    if (s == 0) {
                        Q[(size_t)r * 128 + c] = __float2bfloat16(v);
                    } else if (s == 3) {
                        S[(size_t)r * 128 + c] = v;
                    } else {
                        kv[(size_t)r * 256 + ((s == 2) ? 128 : 0) + c] = __float2bfloat16(v);
                    }
                }
            }
        }
    }
}

// ---------------- fused attention + beta gate + residual + layernorm ----------------
// one wave per node; 64 lanes = 8 edge-slots x 8 heads; lane owns a head's 16 dims.
// e handled algebraically: score via inline qm, V-side via S0..S2,den with Me.
__global__ __launch_bounds__(256) void attn_k(
    const int* __restrict__ off, const int* __restrict__ el_src,
    const float4* __restrict__ ea4, const float* __restrict__ Me,
    const bf16* __restrict__ Q, const bf16* __restrict__ kv,
    const float* __restrict__ S,
    float* __restrict__ h, bf16* __restrict__ h_bf,
    const float* __restrict__ Wb, const float* __restrict__ lng,
    const float* __restrict__ lnb, int N) {
    int gw = (blockIdx.x * 256 + threadIdx.x) >> 6;
    int l = threadIdx.x & 63;
    int nw = (gridDim.x * 256) >> 6;
    int hh = l & 7, sl = l >> 3;
    int d0 = hh * 16 + sl * 2, d1 = d0 + 1;
    float me00 = Me[d0],       me01 = Me[d1];
    float me10 = Me[128 + d0], me11 = Me[128 + d1];
    float me20 = Me[256 + d0], me21 = Me[256 + d1];
    float me30 = Me[384 + d0], me31 = Me[384 + d1];
    float wba0 = Wb[d0],       wba1 = Wb[d1];
    float wbb0 = Wb[128 + d0], wbb1 = Wb[128 + d1];
    float wbc0 = Wb[256 + d0], wbc1 = Wb[256 + d1];
    float g0 = lng[d0], g1 = lng[d1];
    float bb0 = lnb[d0], bb1 = lnb[d1];
    for (int n = gw; n < N; n += nw) {
        const unsigned* qr = (const unsigned*)Q + (size_t)n * 64 + hh * 8;
        unsigned qq[8];
        *(uint4*)&qq[0] = *(const uint4*)qr;
        *(uint4*)&qq[4] = *(const uint4*)(qr + 4);
        float q[16];
#pragma unroll
        for (int k = 0; k < 8; ++k) { q[2 * k] = blo(qq[k]); q[2 * k + 1] = bhi(qq[k]); }
        // qm_j = q . Me_j over this head's 16 dims (redundant across sl lanes, free)
        float qm0 = 0.f, qm1 = 0.f, qm2 = 0.f, qm3 = 0.f;
#pragma unroll
        for (int c = 0; c < 4; ++c) {
            float4 r0 = *(const float4*)(Me + hh * 16 + c * 4);
            float4 r1 = *(const float4*)(Me + 128 + hh * 16 + c * 4);
            float4 r2 = *(const float4*)(Me + 256 + hh * 16 + c * 4);
            float4 r3 = *(const float4*)(Me + 384 + hh * 16 + c * 4);
            qm0 += q[c*4]*r0.x + q[c*4+1]*r0.y + q[c*4+2]*r0.z + q[c*4+3]*r0.w;
            qm1 += q[c*4]*r1.x + q[c*4+1]*r1.y + q[c*4+2]*r1.z + q[c*4+3]*r1.w;
            qm2 += q[c*4]*r2.x + q[c*4+1]*r2.y + q[c*4+2]*r2.z + q[c*4+3]*r2.w;
            qm3 += q[c*4]*r3.x + q[c*4+1]*r3.y + q[c*4+2]*r3.z + q[c*4+3]*r3.w;
        }
        float acc[16] = {};
        float S0 = 0.f, S1 = 0.f, S2 = 0.f, den = 0.f;
        int i0 = off[n], i1 = off[n + 1];
        int nit = (i1 - i0 + 7) >> 3;
        for (int it = 0; it < nit; ++it) {
            int idx = i0 + it * 8 + sl;
            bool ok = idx < i1;
            int ci = ok ? idx : i0;
            int src = el_src[ci];
            float4 ae = ea4[ci];
            const unsigned* kr = (const unsigned*)kv + (size_t)src * 128 + hh * 8;
            unsigned kk[8], vv[8];
            *(uint4*)&kk[0] = *(const uint4*)kr;
            *(uint4*)&kk[4] = *(const uint4*)(kr + 4);
            *(uint4*)&vv[0] = *(const uint4*)(kr + 64);
            *(uint4*)&vv[4] = *(const uint4*)(kr + 68);
            float sd = fmaf(ae.x, qm0, fmaf(ae.y, qm1, fmaf(ae.z, qm2, qm3)));
#pragma unroll
            for (int k = 0; k < 8; ++k)
                sd = fmaf(q[2 * k], blo(kk[k]), fmaf(q[2 * k + 1], bhi(kk[k]), sd));
            float p = ok ? __expf(sd * 0.25f) : 0.f;
            den += p;
            S0 = fmaf(p, ae.x, S0);
            S1 = fmaf(p, ae.y, S1);
            S2 = fmaf(p, ae.z, S2);
#pragma unroll
            for (int k = 0; k < 8; ++k) {
                acc[2 * k]     = fmaf(p, blo(vv[k]), acc[2 * k]);
                acc[2 * k + 1] = fmaf(p, bhi(vv[k]), acc[2 * k + 1]);
            }
        }
        // reduce over the 8 edge-slot lanes of each head
        den = red8(den); S0 = red8(S0); S1 = red8(S1); S2 = red8(S2);
#pragma unroll
        for (int k = 0; k < 16; ++k) acc[k] = red8(acc[k]);
        float inv = den > 0.f ? 1.f / den : 0.f;
        float o0 = (acc[sl * 2]     + S0 * me00 + S1 * me10 + S2 * me20 + den * me30) * inv;
        float o1 = (acc[sl * 2 + 1] + S0 * me01 + S1 * me11 + S2 * me21 + den * me31) * inv;
        size_t base = (size_t)n * 128;
        float s0 = S[base + d0], s1 = S[base + d1];
        float part = o0 * wba0 + s0 * wbb0 + (o0 - s0) * wbc0
                   + o1 * wba1 + s1 * wbb1 + (o1 - s1) * wbc1;
        float g = waveReduceSum(part);
        float beta = 1.f / (1.f + __expf(-g));
        float y0 = beta * s0 + (1.f - beta) * o0;
        float y1 = beta * s1 + (1.f - beta) * o1;
        float z0 = y0 + h[base + d0];
        float z1 = y1 + h[base + d1];
        float mean = waveReduceSum(z0 + z1) * (1.f / 128.f);
        float c0 = z0 - mean, c1 = z1 - mean;
        float var = waveReduceSum(c0 * c0 + c1 * c1) * (1.f / 128.f);
        float invs = rsqrtf(var + 1e-5f);
        float r0 = c0 * invs * g0 + bb0;
        float r1 = c1 * invs * g1 + bb1;
        h[base + d0] = r0;
        h[base + d1] = r1;
        h_bf[base + d0] = __float2bfloat16(r0);
        h_bf[base + d1] = __float2bfloat16(r1);
    }
}

// ---------------- two-stage pooling + head ----------------
__global__ __launch_bounds__(256) void pool_partial_k(
    const float* __restrict__ h, const int* __restrict__ batch,
    float* __restrict__ psum, int N) {
    int d = threadIdx.x & 127;
    int half = threadIdx.x >> 7;
    int n0 = blockIdx.x * 64;
    int n1 = min(n0 + 64, N);
    float acc = 0.f;
    int curg = -1;
    for (int n = n0 + half; n < n1; n += 2) {
        int g = batch[n];
        if (g != curg) {
            if (curg >= 0) atomicAdd(&psum[curg * 128 + d], acc);
            acc = 0.f;
            curg = g;
        }
        acc += h[(size_t)n * 128 + d];
    }
    if (curg >= 0) atomicAdd(&psum[curg * 128 + d], acc);
}

__global__ __launch_bounds__(128) void head2_k(
    const float* __restrict__ psum, const int* __restrict__ batch,
    const float* __restrict__ h1w, const float* __restrict__ h1b,
    const float* __restrict__ h2w, const float* __restrict__ h2b,
    float* __restrict__ out, int N) {
    int g = blockIdx.x;
    int t = threadIdx.x;
    auto lb = [&](int val) {
        int lo = 0, hi = N;
        while (lo < hi) {
            int mid = (lo + hi) >> 1;
            if (batch[mid] < val) lo = mid + 1; else hi = mid;
        }
        return lo;
    };
    int s = lb(g), e = lb(g + 1);
    float cnt = fmaxf((float)(e - s), 1.f);
    __shared__ float pl[128];
    __shared__ float hid[64];
    pl[t] = psum[g * 128 + t] / cnt;
    __syncthreads();
    if (t < 64) {
        float a = h1b[t];
        for (int k = 0; k < 128; ++k) a += pl[k] * h1w[k * 64 + t];
        hid[t] = fmaxf(a, 0.f);
    }
    __syncthreads();
    if (t < 10) {
        float o = h2b[t];
        for (int k = 0; k < 64; ++k) o += hid[k] * h2w[k * 10 + t];
        out[g * 10 + t] = o;
    }
}

extern "C" void kernel_launch(void* const* d_in, const int* in_sizes, int n_in,
                              void* d_out, int out_size, void* d_ws, size_t ws_size,
                              hipStream_t stream) {
    const float* x      = (const float*)d_in[0];
    const int*   ei     = (const int*)d_in[1];
    const float* eattr  = (const float*)d_in[2];
    const int*   batch  = (const int*)d_in[3];
    const float* node_w = (const float*)d_in[4];
    const float* node_b = (const float*)d_in[5];
    const float* edge_w = (const float*)d_in[6];
    const float* edge_b = (const float*)d_in[7];
    const float* Wq     = (const float*)d_in[8];
    const float* bq     = (const float*)d_in[9];
    const float* Wk     = (const float*)d_in[10];
    const float* bk     = (const float*)d_in[11];
    const float* Wv     = (const float*)d_in[12];
    const float* bv     = (const float*)d_in[13];
    const float* We     = (const float*)d_in[14];
    const float* Wskip  = (const float*)d_in[15];
    const float* bskip  = (const float*)d_in[16];
    const float* Wbeta  = (const float*)d_in[17];
    const float* ln_g   = (const float*)d_in[18];
    const float* ln_b   = (const float*)d_in[19];
    const float* h1_w   = (const float*)d_in[20];
    const float* h1_b   = (const float*)d_in[21];
    const float* h2_w   = (const float*)d_in[22];
    const float* h2_b   = (const float*)d_in[23];
    float* out = (float*)d_out;

    const int N = in_sizes[3];
    const int E = in_sizes[2] / 3;
    const int L = in_sizes[8] / 16384;
    const int G = out_size / 10;

    char* wptr = (char*)d_ws;
    auto alloc = [&](size_t bytes) {
        char* p = wptr;
        wptr += (bytes + 255) & ~(size_t)255;
        return p;
    };
    float* h      = (float*)alloc((size_t)(N + 64) * 128 * 4);
    bf16*  h_bf   = (bf16*)alloc((size_t)(N + 64) * 128 * 2);
    bf16*  Qb     = (bf16*)alloc((size_t)(N + 64) * 128 * 2);
    bf16*  kv     = (bf16*)alloc((size_t)(N + 64) * 256 * 2);
    float* S      = (float*)alloc((size_t)(N + 64) * 128 * 4);
    float4* ea4   = (float4*)alloc((size_t)E * 16);
    bf16*  Wpack  = (bf16*)alloc((size_t)4 * L * 16384 * 2);
    float* bpack  = (float*)alloc((size_t)4 * L * 128 * 4);
    float* Me     = (float*)alloc((size_t)L * 4 * 128 * 4);
    // deg + psum adjacent -> single memset covers both
    size_t degBytes = ((size_t)N * 4 + 255) & ~(size_t)255;
    char*  zblock = (char*)alloc(degBytes + (size_t)G * 128 * 4);
    int*   deg    = (int*)zblock;
    float* psum   = (float*)(zblock + degBytes);
    int*   off    = (int*)alloc((size_t)(N + 1) * 4);
    int*   cursor = (int*)alloc((size_t)N * 4);
    int*   el_src = (int*)alloc((size_t)E * 4);

    dim3 b256(256), b128(128);

    // one-time prep (single fused kernel + single memset)
    int prepTot = 4 * L * 16384 + 4 * L * 128 + L * 4 * 128;
    prep_k<<<(prepTot + 255) / 256, b256, 0, stream>>>(
        Wq, Wk, Wv, Wskip, bq, bk, bv, bskip, edge_w, edge_b, We,
        Wpack, bpack, Me, L);
    hipMemsetAsync(zblock, 0, degBytes + (size_t)G * 128 * 4, stream);
    hist_k<<<(E + 255) / 256, b256, 0, stream>>>(ei, deg, E);
    scan_k<<<1, 1024, 0, stream>>>(deg, off, cursor, N, E);
    fill_k<<<(E + 255) / 256, b256, 0, stream>>>(ei, eattr, cursor, el_src, ea4, E);
    node_enc_k<<<(N * 128 + 255) / 256, b256, 0, stream>>>(x, node_w, node_b, h, h_bf, N);

    int gN = (N + 63) / 64;
    int gAttn = (N + 3) / 4;
    for (int l = 0; l < L; ++l) {
        const float* Me_l = Me + (size_t)l * 512;
        qkvs_k<<<gN, b256, 0, stream>>>(h_bf, Wpack + (size_t)l * 4 * 16384,
                                        bpack + (size_t)l * 4 * 128, Qb, kv, S, N);
        attn_k<<<gAttn, b256, 0, stream>>>(off, el_src, ea4, Me_l,
                                           Qb, kv, S, h, h_bf,
                                           Wbeta + (size_t)l * 384,
                                           ln_g + (size_t)l * 128, ln_b + (size_t)l * 128, N);
    }

    pool_partial_k<<<gN, b256, 0, stream>>>(h, batch, psum, N);
    head2_k<<<G, b128, 0, stream>>>(psum, batch, h1_w, h1_b, h2_w, h2_b, out, N);
}

// Round 12
// 370.503 us; speedup vs baseline: 1.1885x; 1.1584x over previous
//
#include <hip/hip_runtime.h>
#include <hip/hip_bf16.h>

typedef __hip_bfloat16 bf16;
typedef __attribute__((ext_vector_type(8))) short short8;
typedef __attribute__((ext_vector_type(4))) float f32x4;

#define DEV __device__ __forceinline__

DEV float blo(unsigned u) { return __uint_as_float(u << 16); }
DEV float bhi(unsigned u) { return __uint_as_float(u & 0xffff0000u); }

DEV float waveReduceSum(float v) {
#pragma unroll
    for (int m = 1; m < 64; m <<= 1) v += __shfl_xor(v, m);
    return v;
}

DEV float red8(float v) {  // sum over the 8 lanes with stride 8 (same head)
    v += __shfl_xor(v, 8);
    v += __shfl_xor(v, 16);
    v += __shfl_xor(v, 32);
    return v;
}

// ---------------- fused one-time prep: weight packing + bias packing + Me ----------------
__global__ __launch_bounds__(256) void prep_k(
    const float* __restrict__ Wq, const float* __restrict__ Wk,
    const float* __restrict__ Wv, const float* __restrict__ Ws,
    const float* __restrict__ bq, const float* __restrict__ bk,
    const float* __restrict__ bv, const float* __restrict__ bs,
    const float* __restrict__ edge_w, const float* __restrict__ edge_b,
    const float* __restrict__ We,
    bf16* __restrict__ Wpack, float* __restrict__ bpack, float* __restrict__ Me, int L) {
    int t = blockIdx.x * 256 + threadIdx.x;
    int tA = 4 * L * 16384, tB = 4 * L * 128, tC = L * 4 * 128;
    if (t < tA) {
        int p = t & 16383;
        int ls = t >> 14;
        int l = ls >> 2, s = ls & 3;
        int j = p & 7, ln = (p >> 3) & 63, kb = (p >> 9) & 3, nb = p >> 11;
        int k = kb * 32 + (ln >> 4) * 8 + j;
        int n = nb * 16 + (ln & 15);
        const float* W = (s == 0) ? Wq : (s == 1) ? Wk : (s == 2) ? Wv : Ws;
        Wpack[t] = __float2bfloat16(W[(size_t)l * 16384 + k * 128 + n]);
        return;
    }
    t -= tA;
    if (t < tB) {
        int d = t & 127;
        int ls = t >> 7;
        int l = ls >> 2, s = ls & 3;
        const float* B = (s == 0) ? bq : (s == 1) ? bk : (s == 2) ? bv : bs;
        bpack[t] = B[l * 128 + d];
        return;
    }
    t -= tB;
    if (t < tC) {
        int n = t & 127, j = (t >> 7) & 3, l = t >> 9;
        const float* W = We + (size_t)l * 16384;
        const float* row = (j < 3) ? (edge_w + j * 128) : edge_b;
        float acc = 0.f;
        for (int d = 0; d < 128; ++d) acc += row[d] * W[d * 128 + n];
        Me[t] = acc;
    }
}

// ---------------- CSR build ----------------
__global__ __launch_bounds__(256) void hist_k(const int* __restrict__ ei,
                                              int* __restrict__ deg, int E) {
    int e = blockIdx.x * 256 + threadIdx.x;
    if (e >= E) return;
    atomicAdd(&deg[ei[E + e]], 1);
}

__global__ __launch_bounds__(1024) void scan_k(const int* __restrict__ deg,
                                               int* __restrict__ off,
                                               int* __restrict__ cursor, int N, int E) {
    __shared__ int part[1024];
    int t = threadIdx.x;
    int chunk = (N + 1023) >> 10;
    int lo = t * chunk, hi = min(lo + chunk, N);
    int s = 0;
    for (int i = lo; i < hi; ++i) s += deg[i];
    part[t] = s;
    __syncthreads();
    for (int d = 1; d < 1024; d <<= 1) {
        int v = (t >= d) ? part[t - d] : 0;
        __syncthreads();
        part[t] += v;
        __syncthreads();
    }
    int base = (t == 0) ? 0 : part[t - 1];
    for (int i = lo; i < hi; ++i) {
        off[i] = base;
        cursor[i] = base;
        base += deg[i];
    }
    if (t == 1023) off[N] = E;
}

// scatter src id + edge_attr (padded float4) into CSR position order
__global__ __launch_bounds__(256) void fill_k(const int* __restrict__ ei,
                                              const float* __restrict__ eattr,
                                              int* __restrict__ cursor,
                                              int* __restrict__ el_src,
                                              float4* __restrict__ ea4, int E) {
    int e = blockIdx.x * 256 + threadIdx.x;
    if (e >= E) return;
    int dst = ei[E + e];
    int pos = atomicAdd(&cursor[dst], 1);
    el_src[pos] = ei[e];
    ea4[pos] = make_float4(eattr[e * 3], eattr[e * 3 + 1], eattr[e * 3 + 2], 0.f);
}

// ---------------- node encoder ----------------
__global__ __launch_bounds__(256) void node_enc_k(
    const float* __restrict__ x, const float* __restrict__ w,
    const float* __restrict__ b, float* __restrict__ h,
    bf16* __restrict__ h_bf, int N) {
    int t = blockIdx.x * 256 + threadIdx.x;
    if (t >= N * 128) return;
    int n = t >> 7, d = t & 127;
    float acc = b[d];
#pragma unroll
    for (int i = 0; i < 9; ++i) acc += x[n * 9 + i] * w[i * 128 + d];
    float r = fmaxf(acc, 0.f);
    h[t] = r;
    h_bf[t] = __float2bfloat16(r);
}

// ---------------- fused QKVS MFMA GEMM: [M,128] x [128,128] x4 ----------------
// Q -> [n][128] bf16; K,V -> kv [n][256] bf16 (K row then V row); S -> f32
__global__ __launch_bounds__(256) void qkvs_k(
    const bf16* __restrict__ A, const bf16* __restrict__ Wp,
    const float* __restrict__ bp,
    bf16* __restrict__ Q, bf16* __restrict__ kv,
    float* __restrict__ S, int M) {
    int tid = threadIdx.x;
    int l = tid & 63, w = tid >> 6;
    int row0 = blockIdx.x * 64;
    const short* Ab = (const short*)A + (size_t)(row0 + (l & 15)) * 128 + ((l >> 4) * 8);
    short8 a[4][4];
#pragma unroll
    for (int mb = 0; mb < 4; ++mb)
#pragma unroll
        for (int kb = 0; kb < 4; ++kb)
            a[mb][kb] = *(const short8*)(Ab + mb * 16 * 128 + kb * 32);
    int colb = w * 32 + (l & 15);
#pragma unroll
    for (int s = 0; s < 4; ++s) {
        const short* Wb = (const short*)Wp + s * 16384;
        short8 bfr[2][4];
#pragma unroll
        for (int nbi = 0; nbi < 2; ++nbi)
#pragma unroll
            for (int kb = 0; kb < 4; ++kb)
                bfr[nbi][kb] = *(const short8*)(Wb + (size_t)(((w * 2 + nbi) * 4 + kb) * 64 + l) * 8);
        f32x4 acc[4][2] = {};
#pragma unroll
        for (int kb = 0; kb < 4; ++kb)
#pragma unroll
            for (int mb = 0; mb < 4; ++mb)
#pragma unroll
                for (int nbi = 0; nbi < 2; ++nbi)
                    acc[mb][nbi] = __builtin_amdgcn_mfma_f32_16x16x32_bf16(
                        a[mb][kb], bfr[nbi][kb], acc[mb][nbi], 0, 0, 0);
        float bias0 = bp[s * 128 + colb];
        float bias1 = bp[s * 128 + colb + 16];
#pragma unroll
        for (int mb = 0; mb < 4; ++mb) {
            int rbase = row0 + mb * 16 + (l >> 4) * 4;
#pragma unroll
            for (int j = 0; j < 4; ++j) {
                int r = rbase + j;
                if (r >= M) continue;
#pragma unroll
                for (int nbi = 0; nbi < 2; ++nbi) {
                    int c = colb + nbi * 16;
                    float v = acc[mb][nbi][j] + (nbi ? bias1 : bias0);
                    if (s == 0) {
                        Q[(size_t)r * 128 + c] = __float2bfloat16(v);
                    } else if (s == 3) {
                        S[(size_t)r * 128 + c] = v;
                    } else {
                        kv[(size_t)r * 256 + ((s == 2) ? 128 : 0) + c] = __float2bfloat16(v);
                    }
                }
            }
        }
    }
}

// ---------------- per-(node,head) q . Me_j dots: qm[n*8+h] = {j0,j1,j2,bias} ----------------
__global__ __launch_bounds__(256) void qm_k(
    const bf16* __restrict__ Q, const float* __restrict__ Me,
    float4* __restrict__ qm, int N) {
    int t = blockIdx.x * 256 + threadIdx.x;
    if (t >= N * 8) return;
    int n = t >> 3, hh = t & 7;
    const unsigned* qr = (const unsigned*)Q + (size_t)n * 64 + hh * 8;
    unsigned qq[8];
    *(uint4*)&qq[0] = *(const uint4*)qr;
    *(uint4*)&qq[4] = *(const uint4*)(qr + 4);
    float a0 = 0.f, a1 = 0.f, a2 = 0.f, a3 = 0.f;
#pragma unroll
    for (int k = 0; k < 8; ++k) {
        float x0 = blo(qq[k]), x1 = bhi(qq[k]);
        int d = hh * 16 + 2 * k;
        a0 += x0 * Me[d]       + x1 * Me[d + 1];
        a1 += x0 * Me[128 + d] + x1 * Me[128 + d + 1];
        a2 += x0 * Me[256 + d] + x1 * Me[256 + d + 1];
        a3 += x0 * Me[384 + d] + x1 * Me[384 + d + 1];
    }
    qm[t] = make_float4(a0, a1, a2, a3);
}

// ---------------- fused attention + beta gate + residual + layernorm ----------------
// one wave per node; 64 lanes = 8 edge-slots x 8 heads; lane owns a head's 16 dims.
// e handled algebraically: score via qm, V-side via S0..S2,den post-multiply with Me.
__global__ __launch_bounds__(256) void attn_k(
    const int* __restrict__ off, const int* __restrict__ el_src,
    const float4* __restrict__ ea4, const float* __restrict__ Me,
    const float4* __restrict__ qm, const bf16* __restrict__ Q,
    const bf16* __restrict__ kv, const float* __restrict__ S,
    float* __restrict__ h, bf16* __restrict__ h_bf,
    const float* __restrict__ Wb, const float* __restrict__ lng,
    const float* __restrict__ lnb, int N) {
    int gw = (blockIdx.x * 256 + threadIdx.x) >> 6;
    int l = threadIdx.x & 63;
    int nw = (gridDim.x * 256) >> 6;
    int hh = l & 7, sl = l >> 3;
    int d0 = hh * 16 + sl * 2, d1 = d0 + 1;
    float me00 = Me[d0],       me01 = Me[d1];
    float me10 = Me[128 + d0], me11 = Me[128 + d1];
    float me20 = Me[256 + d0], me21 = Me[256 + d1];
    float me30 = Me[384 + d0], me31 = Me[384 + d1];
    float wba0 = Wb[d0],       wba1 = Wb[d1];
    float wbb0 = Wb[128 + d0], wbb1 = Wb[128 + d1];
    float wbc0 = Wb[256 + d0], wbc1 = Wb[256 + d1];
    float g0 = lng[d0], g1 = lng[d1];
    float bb0 = lnb[d0], bb1 = lnb[d1];
    for (int n = gw; n < N; n += nw) {
        const unsigned* qr = (const unsigned*)Q + (size_t)n * 64 + hh * 8;
        unsigned qq[8];
        *(uint4*)&qq[0] = *(const uint4*)qr;
        *(uint4*)&qq[4] = *(const uint4*)(qr + 4);
        float q[16];
#pragma unroll
        for (int k = 0; k < 8; ++k) { q[2 * k] = blo(qq[k]); q[2 * k + 1] = bhi(qq[k]); }
        float4 qmv = qm[(size_t)n * 8 + hh];
        float acc[16] = {};
        float S0 = 0.f, S1 = 0.f, S2 = 0.f, den = 0.f;
        int i0 = off[n], i1 = off[n + 1];
        int nit = (i1 - i0 + 7) >> 3;
        for (int it = 0; it < nit; ++it) {
            int idx = i0 + it * 8 + sl;
            bool ok = idx < i1;
            int ci = ok ? idx : i0;
            int src = el_src[ci];
            float4 ae = ea4[ci];
            const unsigned* kr = (const unsigned*)kv + (size_t)src * 128 + hh * 8;
            unsigned kk[8], vv[8];
            *(uint4*)&kk[0] = *(const uint4*)kr;
            *(uint4*)&kk[4] = *(const uint4*)(kr + 4);
            *(uint4*)&vv[0] = *(const uint4*)(kr + 64);
            *(uint4*)&vv[4] = *(const uint4*)(kr + 68);
            float sd = fmaf(ae.x, qmv.x, fmaf(ae.y, qmv.y, fmaf(ae.z, qmv.z, qmv.w)));
#pragma unroll
            for (int k = 0; k < 8; ++k)
                sd = fmaf(q[2 * k], blo(kk[k]), fmaf(q[2 * k + 1], bhi(kk[k]), sd));
            float p = ok ? __expf(sd * 0.25f) : 0.f;
            den += p;
            S0 = fmaf(p, ae.x, S0);
            S1 = fmaf(p, ae.y, S1);
            S2 = fmaf(p, ae.z, S2);
#pragma unroll
            for (int k = 0; k < 8; ++k) {
                acc[2 * k]     = fmaf(p, blo(vv[k]), acc[2 * k]);
                acc[2 * k + 1] = fmaf(p, bhi(vv[k]), acc[2 * k + 1]);
            }
        }
        // reduce over the 8 edge-slot lanes of each head
        den = red8(den); S0 = red8(S0); S1 = red8(S1); S2 = red8(S2);
#pragma unroll
        for (int k = 0; k < 16; ++k) acc[k] = red8(acc[k]);
        float inv = den > 0.f ? 1.f / den : 0.f;
        float o0 = (acc[sl * 2]     + S0 * me00 + S1 * me10 + S2 * me20 + den * me30) * inv;
        float o1 = (acc[sl * 2 + 1] + S0 * me01 + S1 * me11 + S2 * me21 + den * me31) * inv;
        size_t base = (size_t)n * 128;
        float s0 = S[base + d0], s1 = S[base + d1];
        float part = o0 * wba0 + s0 * wbb0 + (o0 - s0) * wbc0
                   + o1 * wba1 + s1 * wbb1 + (o1 - s1) * wbc1;
        float g = waveReduceSum(part);
        float beta = 1.f / (1.f + __expf(-g));
        float y0 = beta * s0 + (1.f - beta) * o0;
        float y1 = beta * s1 + (1.f - beta) * o1;
        float z0 = y0 + h[base + d0];
        float z1 = y1 + h[base + d1];
        float mean = waveReduceSum(z0 + z1) * (1.f / 128.f);
        float c0 = z0 - mean, c1 = z1 - mean;
        float var = waveReduceSum(c0 * c0 + c1 * c1) * (1.f / 128.f);
        float invs = rsqrtf(var + 1e-5f);
        float r0 = c0 * invs * g0 + bb0;
        float r1 = c1 * invs * g1 + bb1;
        h[base + d0] = r0;
        h[base + d1] = r1;
        h_bf[base + d0] = __float2bfloat16(r0);
        h_bf[base + d1] = __float2bfloat16(r1);
    }
}

// ---------------- two-stage pooling + head ----------------
__global__ __launch_bounds__(256) void pool_partial_k(
    const float* __restrict__ h, const int* __restrict__ batch,
    float* __restrict__ psum, int N) {
    int d = threadIdx.x & 127;
    int half = threadIdx.x >> 7;
    int n0 = blockIdx.x * 64;
    int n1 = min(n0 + 64, N);
    float acc = 0.f;
    int curg = -1;
    for (int n = n0 + half; n < n1; n += 2) {
        int g = batch[n];
        if (g != curg) {
            if (curg >= 0) atomicAdd(&psum[curg * 128 + d], acc);
            acc = 0.f;
            curg = g;
        }
        acc += h[(size_t)n * 128 + d];
    }
    if (curg >= 0) atomicAdd(&psum[curg * 128 + d], acc);
}

__global__ __launch_bounds__(128) void head2_k(
    const float* __restrict__ psum, const int* __restrict__ batch,
    const float* __restrict__ h1w, const float* __restrict__ h1b,
    const float* __restrict__ h2w, const float* __restrict__ h2b,
    float* __restrict__ out, int N) {
    int g = blockIdx.x;
    int t = threadIdx.x;
    auto lb = [&](int val) {
        int lo = 0, hi = N;
        while (lo < hi) {
            int mid = (lo + hi) >> 1;
            if (batch[mid] < val) lo = mid + 1; else hi = mid;
        }
        return lo;
    };
    int s = lb(g), e = lb(g + 1);
    float cnt = fmaxf((float)(e - s), 1.f);
    __shared__ float pl[128];
    __shared__ float hid[64];
    pl[t] = psum[g * 128 + t] / cnt;
    __syncthreads();
    if (t < 64) {
        float a = h1b[t];
        for (int k = 0; k < 128; ++k) a += pl[k] * h1w[k * 64 + t];
        hid[t] = fmaxf(a, 0.f);
    }
    __syncthreads();
    if (t < 10) {
        float o = h2b[t];
        for (int k = 0; k < 64; ++k) o += hid[k] * h2w[k * 10 + t];
        out[g * 10 + t] = o;
    }
}

extern "C" void kernel_launch(void* const* d_in, const int* in_sizes, int n_in,
                              void* d_out, int out_size, void* d_ws, size_t ws_size,
                              hipStream_t stream) {
    const float* x      = (const float*)d_in[0];
    const int*   ei     = (const int*)d_in[1];
    const float* eattr  = (const float*)d_in[2];
    const int*   batch  = (const int*)d_in[3];
    const float* node_w = (const float*)d_in[4];
    const float* node_b = (const float*)d_in[5];
    const float* edge_w = (const float*)d_in[6];
    const float* edge_b = (const float*)d_in[7];
    const float* Wq     = (const float*)d_in[8];
    const float* bq     = (const float*)d_in[9];
    const float* Wk     = (const float*)d_in[10];
    const float* bk     = (const float*)d_in[11];
    const float* Wv     = (const float*)d_in[12];
    const float* bv     = (const float*)d_in[13];
    const float* We     = (const float*)d_in[14];
    const float* Wskip  = (const float*)d_in[15];
    const float* bskip  = (const float*)d_in[16];
    const float* Wbeta  = (const float*)d_in[17];
    const float* ln_g   = (const float*)d_in[18];
    const float* ln_b   = (const float*)d_in[19];
    const float* h1_w   = (const float*)d_in[20];
    const float* h1_b   = (const float*)d_in[21];
    const float* h2_w   = (const float*)d_in[22];
    const float* h2_b   = (const float*)d_in[23];
    float* out = (float*)d_out;

    const int N = in_sizes[3];
    const int E = in_sizes[2] / 3;
    const int L = in_sizes[8] / 16384;
    const int G = out_size / 10;

    char* wptr = (char*)d_ws;
    auto alloc = [&](size_t bytes) {
        char* p = wptr;
        wptr += (bytes + 255) & ~(size_t)255;
        return p;
    };
    float* h      = (float*)alloc((size_t)(N + 64) * 128 * 4);
    bf16*  h_bf   = (bf16*)alloc((size_t)(N + 64) * 128 * 2);
    bf16*  Qb     = (bf16*)alloc((size_t)(N + 64) * 128 * 2);
    bf16*  kv     = (bf16*)alloc((size_t)(N + 64) * 256 * 2);
    float* S      = (float*)alloc((size_t)(N + 64) * 128 * 4);
    float4* qm    = (float4*)alloc((size_t)N * 8 * 16);
    float4* ea4   = (float4*)alloc((size_t)E * 16);
    bf16*  Wpack  = (bf16*)alloc((size_t)4 * L * 16384 * 2);
    float* bpack  = (float*)alloc((size_t)4 * L * 128 * 4);
    float* Me     = (float*)alloc((size_t)L * 4 * 128 * 4);
    // deg + psum adjacent -> single memset covers both
    size_t degBytes = ((size_t)N * 4 + 255) & ~(size_t)255;
    char*  zblock = (char*)alloc(degBytes + (size_t)G * 128 * 4);
    int*   deg    = (int*)zblock;
    float* psum   = (float*)(zblock + degBytes);
    int*   off    = (int*)alloc((size_t)(N + 1) * 4);
    int*   cursor = (int*)alloc((size_t)N * 4);
    int*   el_src = (int*)alloc((size_t)E * 4);

    dim3 b256(256), b128(128);

    // one-time prep (single fused kernel + single memset)
    int prepTot = 4 * L * 16384 + 4 * L * 128 + L * 4 * 128;
    prep_k<<<(prepTot + 255) / 256, b256, 0, stream>>>(
        Wq, Wk, Wv, Wskip, bq, bk, bv, bskip, edge_w, edge_b, We,
        Wpack, bpack, Me, L);
    hipMemsetAsync(zblock, 0, degBytes + (size_t)G * 128 * 4, stream);
    hist_k<<<(E + 255) / 256, b256, 0, stream>>>(ei, deg, E);
    scan_k<<<1, 1024, 0, stream>>>(deg, off, cursor, N, E);
    fill_k<<<(E + 255) / 256, b256, 0, stream>>>(ei, eattr, cursor, el_src, ea4, E);
    node_enc_k<<<(N * 128 + 255) / 256, b256, 0, stream>>>(x, node_w, node_b, h, h_bf, N);

    int gN = (N + 63) / 64;
    int gAttn = (N + 3) / 4;
    int gQm = (N * 8 + 255) / 256;
    for (int l = 0; l < L; ++l) {
        const float* Me_l = Me + (size_t)l * 512;
        qkvs_k<<<gN, b256, 0, stream>>>(h_bf, Wpack + (size_t)l * 4 * 16384,
                                        bpack + (size_t)l * 4 * 128, Qb, kv, S, N);
        qm_k<<<gQm, b256, 0, stream>>>(Qb, Me_l, qm, N);
        attn_k<<<gAttn, b256, 0, stream>>>(off, el_src, ea4, Me_l, qm,
                                           Qb, kv, S, h, h_bf,
                                           Wbeta + (size_t)l * 384,
                                           ln_g + (size_t)l * 128, ln_b + (size_t)l * 128, N);
    }

    pool_partial_k<<<gN, b256, 0, stream>>>(h, batch, psum, N);
    head2_k<<<G, b128, 0, stream>>>(psum, batch, h1_w, h1_b, h2_w, h2_b, out, N);
}